// Round 3
// baseline (549.768 us; speedup 1.0000x reference)
//
#include <hip/hip_runtime.h>

#define B_   64
#define N_   512
#define M_   512
#define Dm_  64
#define BIGF 1e30f
// gamma = 0.1; work in scaled units R' = R / (gamma*ln2):
//   r' = d' + mn' - log2(2^(mn'-a') + 2^(mn'-b') + 2^(mn'-c'))
#define SINV 14.426950408889634f    // 1/(gamma*ln2)
#define LAG  16                     // inter-wave column lag = barrier period

// ---------------------------------------------------------------------------
// Kernel A: D'[b,i,j] = SINV * sum_k (x[b,i,k]-y[b,j,k])^2  (pre-scaled).
// 128x128 tile, 256 threads, 8x8 micro-tile.
// ---------------------------------------------------------------------------
__global__ __launch_bounds__(256) void dtw_dist_kernel(const float* __restrict__ x,
                                                       const float* __restrict__ y,
                                                       float* __restrict__ D) {
  __shared__ float xs[128][65];
  __shared__ float ys[128][65];
  const int b  = blockIdx.z;
  const int i0 = blockIdx.y * 128;
  const int j0 = blockIdx.x * 128;
  const int tid = threadIdx.x;

  const float* xb = x + ((size_t)b * N_ + i0) * Dm_;
  const float* yb = y + ((size_t)b * M_ + j0) * Dm_;
#pragma unroll
  for (int r = 0; r < 8; ++r) {
    int v4 = tid + r * 256;
    int row = v4 >> 4, c4 = (v4 & 15) * 4;
    float4 xv = *(const float4*)(xb + (size_t)row * Dm_ + c4);
    float4 yv = *(const float4*)(yb + (size_t)row * Dm_ + c4);
    xs[row][c4 + 0] = xv.x; xs[row][c4 + 1] = xv.y;
    xs[row][c4 + 2] = xv.z; xs[row][c4 + 3] = xv.w;
    ys[row][c4 + 0] = yv.x; ys[row][c4 + 1] = yv.y;
    ys[row][c4 + 2] = yv.z; ys[row][c4 + 3] = yv.w;
  }
  __syncthreads();

  const int ty = tid >> 4, tx = tid & 15;
  float acc[8][8];
#pragma unroll
  for (int e = 0; e < 8; ++e)
#pragma unroll
    for (int f = 0; f < 8; ++f) acc[e][f] = 0.f;

#pragma unroll 4
  for (int k = 0; k < Dm_; ++k) {
    float xa[8], yv[8];
#pragma unroll
    for (int e = 0; e < 8; ++e) xa[e] = xs[ty * 8 + e][k];
#pragma unroll
    for (int f = 0; f < 8; ++f) yv[f] = ys[tx * 8 + f][k];
#pragma unroll
    for (int e = 0; e < 8; ++e)
#pragma unroll
      for (int f = 0; f < 8; ++f) {
        float t = xa[e] - yv[f];
        acc[e][f] = fmaf(t, t, acc[e][f]);
      }
  }

  float* Db = D + ((size_t)b * N_ + i0) * M_ + j0;
#pragma unroll
  for (int e = 0; e < 8; ++e) {
    const int row = ty * 8 + e;
#pragma unroll
    for (int f4 = 0; f4 < 2; ++f4) {
      float4 v4 = make_float4(acc[e][f4 * 4 + 0] * SINV, acc[e][f4 * 4 + 1] * SINV,
                              acc[e][f4 * 4 + 2] * SINV, acc[e][f4 * 4 + 3] * SINV);
      *(float4*)(Db + (size_t)row * M_ + tx * 8 + f4 * 4) = v4;
    }
  }
}

// ---------------------------------------------------------------------------
// Kernel B: skewed-pipeline soft-DTW DP, one block (8 waves) per batch.
// Lane t owns row i=t+1; at step s it works column j = s - skew + 1,
// skew = t + wave*LAG. Neighbor value R'[i-1][j] comes from lane t-1's
// previous-step result via DPP wave_shr:1 (full-rate VALU, no LDS latency);
// lane 0 of each wave takes the ring value via the DPP `old` operand.
// Wave boundaries: 32-slot LDS ring per boundary, consumed age = LAG+1
// steps -> strictly one barrier epoch old (per-step publish; provably safe).
// ---------------------------------------------------------------------------
template <bool SEP>
__global__ __launch_bounds__(512) void dtw_dp_kernel(const float* __restrict__ Dmat,
                                                     const float* __restrict__ x,
                                                     float* __restrict__ wv,
                                                     float* __restrict__ out) {
  const int b    = blockIdx.x;
  const int t    = threadIdx.x;   // 0..511
  const int w    = t >> 6;        // wave 0..7
  const int lane = t & 63;
  const int skew = t + w * LAG;

  // 8 rows of 2*LAG slots (row 7 is never written: wave 0 reads it as BIGF),
  // + 1 trash slot for branchless lane-63 publish.
  __shared__ float ringp[8 * 2 * LAG + 1];
  __shared__ float bcast;

  for (int q = t; q < 8 * 2 * LAG + 1; q += 512) ringp[q] = BIGF;
  __syncthreads();

  const float* Drow = Dmat + ((size_t)b * N_ + t) * M_;
  const int rd_base = ((w + 7) & 7) * (2 * LAG);           // wave w reads row w-1 (w=0 -> row 7)
  const int TRASH   = 8 * 2 * LAG;
  const bool pub    = (lane == 63) && (w < 7);
  const int wr_row  = w * (2 * LAG);

  float A = (t == 0) ? 0.0f : BIGF;  // becomes c=R'[0][0]=0 at lane 0's first step
  float B = BIGF;                    // R'[i][0] = BIG
  float r = BIGF;

  float dcur[LAG], dnxt[LAG];
#pragma unroll
  for (int k = 0; k < LAG; ++k) {
    int idx = k - skew; idx = idx < 0 ? 0 : idx;
    dcur[k] = Drow[idx];
  }

  const int NSTEP = N_ + M_ - 1 + (N_ - 64) + 7 * LAG;  // 511+511+1+... = 1135
  const int NBLK  = (NSTEP + LAG - 1) / LAG;            // 71

  for (int blk = 0; blk < NBLK; ++blk) {
    const int s0 = blk * LAG;

    // prefetch next block's d' (clamped; garbage masked by `active`)
#pragma unroll
    for (int k = 0; k < LAG; ++k) {
      int idx = s0 + LAG + k - skew;
      idx = idx < 0 ? 0 : (idx > M_ - 1 ? M_ - 1 : idx);
      dnxt[k] = Drow[idx];
    }

    // ring values for this block: slot (s - (LAG+1)) mod 2LAG; uniform address
    // across the wave -> LDS broadcast read.
    float rvf[LAG];
#pragma unroll
    for (int k = 0; k < LAG; ++k)
      rvf[k] = ringp[rd_base + ((s0 + k + LAG - 1) & (2 * LAG - 1))];

#pragma unroll
    for (int k = 0; k < LAG; ++k) {
      const int s = s0 + k;
#if __has_builtin(__builtin_amdgcn_update_dpp)
      // nb[lane] = r[lane-1]; nb[0] = rvf[k] (old kept at lane 0, bound_ctrl=0)
      const int nb_i = __builtin_amdgcn_update_dpp(__float_as_int(rvf[k]),
                                                   __float_as_int(r),
                                                   0x138 /*wave_shr:1*/, 0xF, 0xF, false);
      const float nb = __int_as_float(nb_i);
#else
      float nb = __shfl_up(r, 1);
      if (lane == 0) nb = rvf[k];
#endif
      const float C = A;                  // R'[i-1][j-1]
      A = nb;                             // R'[i-1][j]
      const int n = s - skew;
      const bool active = (n >= 0) && (n < M_);
      const float mn = fminf(fminf(A, B), C);
      const float e  = exp2f(mn - A) + exp2f(mn - B) + exp2f(mn - C);
      const float rr = (dcur[k] + mn) - log2f(e);
      r = active ? rr : BIGF;
      if (active) B = rr;
      // branchless boundary publish: non-publishers write the trash slot
      const int addr = pub ? (wr_row + (s & (2 * LAG - 1))) : TRASH;
      ringp[addr] = r;
    }
#pragma unroll
    for (int k = 0; k < LAG; ++k) dcur[k] = dnxt[k];
    __syncthreads();
  }

  if (SEP) {
    if (t == N_ - 1) wv[b] = exp2f(-0.1f * B);   // w = exp(-R) = 2^(-gamma*R')
  } else {
    if (t == N_ - 1) bcast = B;
    __syncthreads();
    const float wsc = exp2f(-0.1f * bcast);
    const float4* x4 = (const float4*)(x + (size_t)b * N_ * Dm_);
    float4* o4 = (float4*)(out + (size_t)b * N_ * Dm_);
#pragma unroll
    for (int e = 0; e < (N_ * Dm_ / 4) / 512; ++e) {
      float4 v = x4[e * 512 + t];
      v.x *= wsc; v.y *= wsc; v.z *= wsc; v.w *= wsc;
      o4[e * 512 + t] = v;
    }
  }
}

// ---------------------------------------------------------------------------
// Kernel C: out = x * w[b], full-grid elementwise (float4).
// ---------------------------------------------------------------------------
__global__ __launch_bounds__(256) void dtw_mul_kernel(const float* __restrict__ x,
                                                      const float* __restrict__ wv,
                                                      float* __restrict__ out) {
  const int idx = blockIdx.x * 256 + threadIdx.x;   // float4 index
  const int b = idx >> 13;                          // 8192 float4 per batch
  const float w = wv[b];
  float4 v = ((const float4*)x)[idx];
  v.x *= w; v.y *= w; v.z *= w; v.w *= w;
  ((float4*)out)[idx] = v;
}

// ---------------------------------------------------------------------------
// Fallback (no workspace): barrier-per-step fused DP. Slow but correct.
// ---------------------------------------------------------------------------
__global__ __launch_bounds__(512) void dtw_dp_fused(const float* __restrict__ x,
                                                    const float* __restrict__ y,
                                                    float* __restrict__ out) {
  __shared__ float v[3][516];
  const int b = blockIdx.x;
  const int t = threadIdx.x;
  const int i = t + 1;
  if (t == 0) { v[0][0] = 0.f; v[1][0] = BIGF; v[2][0] = BIGF; }
  v[0][i] = BIGF;
  v[1][i] = BIGF;
  float xr[Dm_];
  const float* xrow = x + ((size_t)b * N_ + t) * Dm_;
#pragma unroll
  for (int k = 0; k < Dm_; ++k) xr[k] = xrow[k];
  __syncthreads();
  int cur = 2, m1 = 1, m2 = 0;
  const float GLN2 = 0.069314718055994531f;
  for (int p = 2; p <= N_ + M_; ++p) {
    const int j = p - i;
    const bool valid = (j >= 1) && (j <= M_);
    float d = 0.f;
    if (valid) {
      const float* yr = y + ((size_t)b * M_ + (j - 1)) * Dm_;
      float a = 0.f;
#pragma unroll
      for (int k = 0; k < Dm_; ++k) { float u = xr[k] - yr[k]; a = fmaf(u, u, a); }
      d = a;
    }
    const float a  = v[m1][i - 1];
    const float bb = v[m1][i];
    const float c  = v[m2][i - 1];
    const float mn = fminf(fminf(a, bb), c);
    const float s = exp2f((mn - a) * SINV) + exp2f((mn - bb) * SINV) +
                    exp2f((mn - c) * SINV);
    const float rr = valid ? (d + mn - GLN2 * log2f(s)) : BIGF;
    v[cur][i] = rr;
    if (t == 0) v[cur][0] = BIGF;
    __syncthreads();
    const int tmp = m2; m2 = m1; m1 = cur; cur = tmp;
  }
  const float dist = v[(N_ + M_) % 3][N_];
  const float wsc = expf(-dist);
  const float* xb = x + (size_t)b * N_ * Dm_;
  float* ob = out + (size_t)b * N_ * Dm_;
#pragma unroll
  for (int e = 0; e < (N_ * Dm_) / 512; ++e) {
    const int idx = e * 512 + t;
    ob[idx] = xb[idx] * wsc;
  }
}

// ---------------------------------------------------------------------------
extern "C" void kernel_launch(void* const* d_in, const int* in_sizes, int n_in,
                              void* d_out, int out_size, void* d_ws, size_t ws_size,
                              hipStream_t stream) {
  const float* x = (const float*)d_in[0];
  const float* y = (const float*)d_in[1];
  float* out = (float*)d_out;

  const size_t need = (size_t)B_ * N_ * M_ * sizeof(float);  // 64 MiB
  if (ws_size >= need + 4096) {
    // D matrix + separate w[] array; full-grid multiply kernel.
    float* Dbuf = (float*)d_ws;
    float* wv   = (float*)((char*)d_ws + need);
    dim3 g(M_ / 128, N_ / 128, B_);
    dtw_dist_kernel<<<g, dim3(256), 0, stream>>>(x, y, Dbuf);
    dtw_dp_kernel<true><<<dim3(B_), dim3(512), 0, stream>>>(Dbuf, x, wv, out);
    dtw_mul_kernel<<<dim3((B_ * N_ * Dm_ / 4) / 256), dim3(256), 0, stream>>>(x, wv, out);
  } else if (ws_size >= need) {
    // exactly-sized workspace: multiply inside the DP kernel
    float* Dbuf = (float*)d_ws;
    dim3 g(M_ / 128, N_ / 128, B_);
    dtw_dist_kernel<<<g, dim3(256), 0, stream>>>(x, y, Dbuf);
    dtw_dp_kernel<false><<<dim3(B_), dim3(512), 0, stream>>>(Dbuf, x, nullptr, out);
  } else {
    dtw_dp_fused<<<dim3(B_), dim3(512), 0, stream>>>(x, y, out);
  }
}

// Round 4
// 370.367 us; speedup vs baseline: 1.4844x; 1.4844x over previous
//
#include <hip/hip_runtime.h>

#define B_   64
#define N_   512
#define M_   512
#define Dm_  64
#define BIGF 1e30f
// gamma = 0.1; work in scaled units R' = R / (gamma*ln2):
//   r' = d' + mn' - log2(2^(mn'-a') + 2^(mn'-b') + 2^(mn'-c'))
#define SINV 14.426950408889634f    // 1/(gamma*ln2)
#define LAG  16                     // inter-wave column lag = barrier period
#define RING 64                     // slots per boundary row (read age LAG+1=17,
                                    // write window 16: provably disjoint mod 64)

// ---------------------------------------------------------------------------
// Kernel A: D'[b,i,j] = SINV * sum_k (x[b,i,k]-y[b,j,k])^2  (pre-scaled).
// 128x128 tile, 256 threads, 8x8 micro-tile.
// ---------------------------------------------------------------------------
__global__ __launch_bounds__(256) void dtw_dist_kernel(const float* __restrict__ x,
                                                       const float* __restrict__ y,
                                                       float* __restrict__ D) {
  __shared__ float xs[128][65];
  __shared__ float ys[128][65];
  const int b  = blockIdx.z;
  const int i0 = blockIdx.y * 128;
  const int j0 = blockIdx.x * 128;
  const int tid = threadIdx.x;

  const float* xb = x + ((size_t)b * N_ + i0) * Dm_;
  const float* yb = y + ((size_t)b * M_ + j0) * Dm_;
#pragma unroll
  for (int r = 0; r < 8; ++r) {
    int v4 = tid + r * 256;
    int row = v4 >> 4, c4 = (v4 & 15) * 4;
    float4 xv = *(const float4*)(xb + (size_t)row * Dm_ + c4);
    float4 yv = *(const float4*)(yb + (size_t)row * Dm_ + c4);
    xs[row][c4 + 0] = xv.x; xs[row][c4 + 1] = xv.y;
    xs[row][c4 + 2] = xv.z; xs[row][c4 + 3] = xv.w;
    ys[row][c4 + 0] = yv.x; ys[row][c4 + 1] = yv.y;
    ys[row][c4 + 2] = yv.z; ys[row][c4 + 3] = yv.w;
  }
  __syncthreads();

  const int ty = tid >> 4, tx = tid & 15;
  float acc[8][8];
#pragma unroll
  for (int e = 0; e < 8; ++e)
#pragma unroll
    for (int f = 0; f < 8; ++f) acc[e][f] = 0.f;

#pragma unroll 4
  for (int k = 0; k < Dm_; ++k) {
    float xa[8], yv[8];
#pragma unroll
    for (int e = 0; e < 8; ++e) xa[e] = xs[ty * 8 + e][k];
#pragma unroll
    for (int f = 0; f < 8; ++f) yv[f] = ys[tx * 8 + f][k];
#pragma unroll
    for (int e = 0; e < 8; ++e)
#pragma unroll
      for (int f = 0; f < 8; ++f) {
        float t = xa[e] - yv[f];
        acc[e][f] = fmaf(t, t, acc[e][f]);
      }
  }

  float* Db = D + ((size_t)b * N_ + i0) * M_ + j0;
#pragma unroll
  for (int e = 0; e < 8; ++e) {
    const int row = ty * 8 + e;
#pragma unroll
    for (int f4 = 0; f4 < 2; ++f4) {
      float4 v4 = make_float4(acc[e][f4 * 4 + 0] * SINV, acc[e][f4 * 4 + 1] * SINV,
                              acc[e][f4 * 4 + 2] * SINV, acc[e][f4 * 4 + 3] * SINV);
      *(float4*)(Db + (size_t)row * M_ + tx * 8 + f4 * 4) = v4;
    }
  }
}

// ---------------------------------------------------------------------------
// Kernel B: skewed-pipeline soft-DTW DP, one block (8 waves) per batch.
// Lane t owns row i=t+1; at step s it works column j = s - skew + 1,
// skew = t + wave*LAG.
//   A = R'[i-1][j]   : lane t-1's r from step s-1 via DPP wave_shr:1 (VALU)
//   B = R'[i][j-1]   : own previous active value (register)
//   C = R'[i-1][j-1] : lane t-1's r from step s-2 (previous A)
// Wave boundaries: RING-slot LDS ring per boundary; ONLY lane 63 of waves
// 0..6 publishes (predicated — R3's all-lane trash write was a same-bank
// write storm). Reader consumes slot (s-LAG-1) mod RING: one barrier epoch
// old, and read/write slot sets are disjoint mod RING.
// ---------------------------------------------------------------------------
template <bool SEP>
__global__ __launch_bounds__(512) void dtw_dp_kernel(const float* __restrict__ Dmat,
                                                     const float* __restrict__ x,
                                                     float* __restrict__ wv,
                                                     float* __restrict__ out) {
  const int b    = blockIdx.x;
  const int t    = threadIdx.x;   // 0..511
  const int w    = t >> 6;        // wave 0..7
  const int lane = t & 63;
  const int skew = t + w * LAG;

  __shared__ float ringp[8 * RING];   // row 7 never written: wave 0 reads BIGF
  __shared__ float bcast;

  for (int q = t; q < 8 * RING; q += 512) ringp[q] = BIGF;
  __syncthreads();

  const float* Drow = Dmat + ((size_t)b * N_ + t) * M_;
  const int rd_base = ((w + 7) & 7) * RING;   // wave w reads row w-1 (w=0 -> row 7)
  const bool pub    = (lane == 63) && (w < 7);
  const int wr_row  = w * RING;

  float A = (t == 0) ? 0.0f : BIGF;  // becomes C=R'[0][0]=0 at lane 0's first step
  float B = BIGF;                    // R'[i][0] = BIG
  float r = BIGF;

  float dcur[LAG], dnxt[LAG];
#pragma unroll
  for (int k = 0; k < LAG; ++k) {
    int idx = k - skew; idx = idx < 0 ? 0 : idx;
    dcur[k] = Drow[idx];
  }

  const int NSTEP = (N_ - 1) + 7 * LAG + M_ + 1;   // 511+112+513 -> 1136 (>=1135)
  const int NBLK  = (NSTEP + LAG - 1) / LAG;       // 71

  for (int blk = 0; blk < NBLK; ++blk) {
    const int s0 = blk * LAG;

    // prefetch next block's d' (clamped; garbage masked by `active`)
#pragma unroll
    for (int k = 0; k < LAG; ++k) {
      int idx = s0 + LAG + k - skew;
      idx = idx < 0 ? 0 : (idx > M_ - 1 ? M_ - 1 : idx);
      dnxt[k] = Drow[idx];
    }

    // ring values for this block: slot (s - LAG - 1) mod RING; uniform address
    // across the wave -> LDS broadcast read. All values published before the
    // previous barrier; write-set {s0..s0+15} and read-set {s0+47..s0+62}
    // (mod 64) are disjoint.
    float rvf[LAG];
#pragma unroll
    for (int k = 0; k < LAG; ++k)
      rvf[k] = ringp[rd_base + ((s0 + k - LAG - 1) & (RING - 1))];

#pragma unroll
    for (int k = 0; k < LAG; ++k) {
      const int s = s0 + k;
#if __has_builtin(__builtin_amdgcn_update_dpp)
      // nb[lane] = r[lane-1]; lane 0 keeps old = rvf[k] (bound_ctrl=0)
      const int nb_i = __builtin_amdgcn_update_dpp(__float_as_int(rvf[k]),
                                                   __float_as_int(r),
                                                   0x138 /*wave_shr:1*/, 0xF, 0xF, false);
      const float nb = __int_as_float(nb_i);
#else
      float nb = __shfl_up(r, 1);
      if (lane == 0) nb = rvf[k];
#endif
      const float C = A;                  // R'[i-1][j-1]
      A = nb;                             // R'[i-1][j]
      const int n = s - skew;
      const bool active = (n >= 0) && (n < M_);
      const float mn = fminf(fminf(A, B), C);
      const float e  = (exp2f(mn - A) + exp2f(mn - B)) + exp2f(mn - C);
      const float rr = (dcur[k] + mn) - log2f(e);
      r = active ? rr : BIGF;
      if (active) B = rr;
      if (pub) ringp[wr_row + (s & (RING - 1))] = r;   // 1 lane/wave publishes
    }
#pragma unroll
    for (int k = 0; k < LAG; ++k) dcur[k] = dnxt[k];
    __syncthreads();
  }

  if (SEP) {
    if (t == N_ - 1) wv[b] = exp2f(-0.1f * B);   // w = exp(-R) = 2^(-gamma*R')
  } else {
    if (t == N_ - 1) bcast = B;
    __syncthreads();
    const float wsc = exp2f(-0.1f * bcast);
    const float4* x4 = (const float4*)(x + (size_t)b * N_ * Dm_);
    float4* o4 = (float4*)(out + (size_t)b * N_ * Dm_);
#pragma unroll
    for (int e = 0; e < (N_ * Dm_ / 4) / 512; ++e) {
      float4 v = x4[e * 512 + t];
      v.x *= wsc; v.y *= wsc; v.z *= wsc; v.w *= wsc;
      o4[e * 512 + t] = v;
    }
  }
}

// ---------------------------------------------------------------------------
// Kernel C: out = x * w[b], full-grid elementwise (float4).
// ---------------------------------------------------------------------------
__global__ __launch_bounds__(256) void dtw_mul_kernel(const float* __restrict__ x,
                                                      const float* __restrict__ wv,
                                                      float* __restrict__ out) {
  const int idx = blockIdx.x * 256 + threadIdx.x;   // float4 index
  const int b = idx >> 13;                          // 8192 float4 per batch
  const float w = wv[b];
  float4 v = ((const float4*)x)[idx];
  v.x *= w; v.y *= w; v.z *= w; v.w *= w;
  ((float4*)out)[idx] = v;
}

// ---------------------------------------------------------------------------
// Fallback (no workspace): barrier-per-step fused DP. Slow but correct.
// ---------------------------------------------------------------------------
__global__ __launch_bounds__(512) void dtw_dp_fused(const float* __restrict__ x,
                                                    const float* __restrict__ y,
                                                    float* __restrict__ out) {
  __shared__ float v[3][516];
  const int b = blockIdx.x;
  const int t = threadIdx.x;
  const int i = t + 1;
  if (t == 0) { v[0][0] = 0.f; v[1][0] = BIGF; v[2][0] = BIGF; }
  v[0][i] = BIGF;
  v[1][i] = BIGF;
  float xr[Dm_];
  const float* xrow = x + ((size_t)b * N_ + t) * Dm_;
#pragma unroll
  for (int k = 0; k < Dm_; ++k) xr[k] = xrow[k];
  __syncthreads();
  int cur = 2, m1 = 1, m2 = 0;
  const float GLN2 = 0.069314718055994531f;
  for (int p = 2; p <= N_ + M_; ++p) {
    const int j = p - i;
    const bool valid = (j >= 1) && (j <= M_);
    float d = 0.f;
    if (valid) {
      const float* yr = y + ((size_t)b * M_ + (j - 1)) * Dm_;
      float a = 0.f;
#pragma unroll
      for (int k = 0; k < Dm_; ++k) { float u = xr[k] - yr[k]; a = fmaf(u, u, a); }
      d = a;
    }
    const float a  = v[m1][i - 1];
    const float bb = v[m1][i];
    const float c  = v[m2][i - 1];
    const float mn = fminf(fminf(a, bb), c);
    const float s = exp2f((mn - a) * SINV) + exp2f((mn - bb) * SINV) +
                    exp2f((mn - c) * SINV);
    const float rr = valid ? (d + mn - GLN2 * log2f(s)) : BIGF;
    v[cur][i] = rr;
    if (t == 0) v[cur][0] = BIGF;
    __syncthreads();
    const int tmp = m2; m2 = m1; m1 = cur; cur = tmp;
  }
  const float dist = v[(N_ + M_) % 3][N_];
  const float wsc = expf(-dist);
  const float* xb = x + (size_t)b * N_ * Dm_;
  float* ob = out + (size_t)b * N_ * Dm_;
#pragma unroll
  for (int e = 0; e < (N_ * Dm_) / 512; ++e) {
    const int idx = e * 512 + t;
    ob[idx] = xb[idx] * wsc;
  }
}

// ---------------------------------------------------------------------------
extern "C" void kernel_launch(void* const* d_in, const int* in_sizes, int n_in,
                              void* d_out, int out_size, void* d_ws, size_t ws_size,
                              hipStream_t stream) {
  const float* x = (const float*)d_in[0];
  const float* y = (const float*)d_in[1];
  float* out = (float*)d_out;

  const size_t need = (size_t)B_ * N_ * M_ * sizeof(float);  // 64 MiB
  if (ws_size >= need + 4096) {
    float* Dbuf = (float*)d_ws;
    float* wvp  = (float*)((char*)d_ws + need);
    dim3 g(M_ / 128, N_ / 128, B_);
    dtw_dist_kernel<<<g, dim3(256), 0, stream>>>(x, y, Dbuf);
    dtw_dp_kernel<true><<<dim3(B_), dim3(512), 0, stream>>>(Dbuf, x, wvp, out);
    dtw_mul_kernel<<<dim3((B_ * N_ * Dm_ / 4) / 256), dim3(256), 0, stream>>>(x, wvp, out);
  } else if (ws_size >= need) {
    float* Dbuf = (float*)d_ws;
    dim3 g(M_ / 128, N_ / 128, B_);
    dtw_dist_kernel<<<g, dim3(256), 0, stream>>>(x, y, Dbuf);
    dtw_dp_kernel<false><<<dim3(B_), dim3(512), 0, stream>>>(Dbuf, x, nullptr, out);
  } else {
    dtw_dp_fused<<<dim3(B_), dim3(512), 0, stream>>>(x, y, out);
  }
}

// Round 5
// 311.696 us; speedup vs baseline: 1.7638x; 1.1882x over previous
//
#include <hip/hip_runtime.h>
#include <hip/hip_bf16.h>

#define B_   64
#define N_   512
#define M_   512
#define Dm_  64
#define BIGF 1e30f
// gamma = 0.1; scaled units R' = R / (gamma*ln2):
//   r' = d' + mn' - log2(2^(mn'-a') + 2^(mn'-b') + 2^(mn'-c'))
#define SINV 14.426950408889634f    // 1/(gamma*ln2)
#define LAG  16                     // inter-wave lag = barrier period
#define RING 64                     // ring slots per wave boundary
#define SPAD 1136                   // padded step count (= 71*16 >= 1135)

// ---------------------------------------------------------------------------
// Kernel A (new): skewed bf16 distance matrix.
//   Ds[b][s][t] = bf16( SINV * ||x[b,t,:] - y[b,s-skew(t),:]||^2 ),
//   skew(t) = t + (t>>6)*LAG.  At DP step s all 512 lanes read row s
//   contiguously -> perfectly coalesced loads in the latency-bound DP.
// ---------------------------------------------------------------------------
__global__ __launch_bounds__(256) void dtw_dist_skew(const float* __restrict__ x,
                                                     const float* __restrict__ y,
                                                     __hip_bfloat16* __restrict__ Ds) {
  __shared__ float xs[128][65];
  __shared__ float ys[128][65];
  const int b  = blockIdx.z;
  const int i0 = blockIdx.y * 128;
  const int j0 = blockIdx.x * 128;
  const int tid = threadIdx.x;

  const float* xb = x + ((size_t)b * N_ + i0) * Dm_;
  const float* yb = y + ((size_t)b * M_ + j0) * Dm_;
#pragma unroll
  for (int r = 0; r < 8; ++r) {
    int v4 = tid + r * 256;
    int row = v4 >> 4, c4 = (v4 & 15) * 4;
    float4 xv = *(const float4*)(xb + (size_t)row * Dm_ + c4);
    float4 yv = *(const float4*)(yb + (size_t)row * Dm_ + c4);
    xs[row][c4 + 0] = xv.x; xs[row][c4 + 1] = xv.y;
    xs[row][c4 + 2] = xv.z; xs[row][c4 + 3] = xv.w;
    ys[row][c4 + 0] = yv.x; ys[row][c4 + 1] = yv.y;
    ys[row][c4 + 2] = yv.z; ys[row][c4 + 3] = yv.w;
  }
  __syncthreads();

  const int ty = tid >> 4, tx = tid & 15;
  float acc[8][8];
#pragma unroll
  for (int e = 0; e < 8; ++e)
#pragma unroll
    for (int f = 0; f < 8; ++f) acc[e][f] = 0.f;

#pragma unroll 4
  for (int k = 0; k < Dm_; ++k) {
    float xa[8], yv[8];
#pragma unroll
    for (int e = 0; e < 8; ++e) xa[e] = xs[ty * 8 + e][k];
#pragma unroll
    for (int f = 0; f < 8; ++f) yv[f] = ys[tx * 8 + f][k];
#pragma unroll
    for (int e = 0; e < 8; ++e)
#pragma unroll
      for (int f = 0; f < 8; ++f) {
        float t = xa[e] - yv[f];
        acc[e][f] = fmaf(t, t, acc[e][f]);
      }
  }

  __hip_bfloat16* base = Ds + (size_t)b * SPAD * N_;
#pragma unroll
  for (int e = 0; e < 8; ++e) {
    const int t  = i0 + ty * 8 + e;
    const int sk = t + (t >> 6) * LAG;
#pragma unroll
    for (int f = 0; f < 8; ++f) {
      const int s = j0 + tx * 8 + f + sk;          // global DP step index
      base[(size_t)s * N_ + t] = __float2bfloat16(acc[e][f] * SINV);
    }
  }
}

// ---------------------------------------------------------------------------
// Kernel B (new): skewed-pipeline DP over the skewed bf16 Ds.
// Lane t owns row i=t+1; at step s computes column j = s - skew + 1.
//   A = R'[i-1][j]   : lane t-1's r @ s-1 via DPP wave_shr:1
//   B = R'[i][j-1]   : own previous value (register)
//   C = R'[i-1][j-1] : lane t-1's r @ s-2 (previous A)
// D loads: Ds row s, contiguous across the block; prefetched LAG steps
// ahead into registers, pinned with sched_barrier(0) fences.
// ---------------------------------------------------------------------------
__global__ __launch_bounds__(512) void dtw_dp2(const ushort* __restrict__ Ds,
                                               float* __restrict__ wv) {
  const int b    = blockIdx.x;
  const int t    = threadIdx.x;   // 0..511
  const int w    = t >> 6;        // wave 0..7
  const int lane = t & 63;
  const int skew = t + w * LAG;

  __shared__ float ringp[8 * RING];   // row 7 never written: wave 0 reads BIGF

  for (int q = t; q < 8 * RING; q += 512) ringp[q] = BIGF;
  __syncthreads();

  const ushort* col = Ds + (size_t)b * SPAD * N_ + t;   // column t, stride N_
  const int rd_base = ((w + 7) & 7) * RING;
  const bool pub    = (lane == 63) && (w < 7);
  const int wr_row  = w * RING;

  float A = (t == 0) ? 0.0f : BIGF;
  float B = BIGF;
  float r = BIGF;

  // prologue: rows 0..15 -> dcur
  float dcur[LAG];
  {
    ushort nx0[LAG];
#pragma unroll
    for (int k = 0; k < LAG; ++k) nx0[k] = col[(size_t)k * N_];
#pragma unroll
    for (int k = 0; k < LAG; ++k) dcur[k] = __uint_as_float((uint)nx0[k] << 16);
  }

  const int NBLK = SPAD / LAG;   // 71
  for (int blk = 0; blk < NBLK; ++blk) {
    const int s0 = blk * LAG;

    // issue next block's coalesced row loads (pin: may not sink past fence)
    ushort nx[LAG];
#pragma unroll
    for (int k = 0; k < LAG; ++k) {
      int sl = s0 + LAG + k; sl = sl > SPAD - 1 ? SPAD - 1 : sl;
      nx[k] = col[(size_t)sl * N_];
    }
    __builtin_amdgcn_sched_barrier(0);

    // ring values (uniform-address LDS broadcast), issued before compute
    float rvf[LAG];
#pragma unroll
    for (int k = 0; k < LAG; ++k)
      rvf[k] = ringp[rd_base + ((s0 + k - LAG - 1) & (RING - 1))];
    __builtin_amdgcn_sched_barrier(0);

#pragma unroll
    for (int k = 0; k < LAG; ++k) {
      const int s = s0 + k;
      // nb[lane] = r[lane-1]; lane 0 keeps old = rvf[k] (bound_ctrl=0)
      const int nb_i = __builtin_amdgcn_update_dpp(__float_as_int(rvf[k]),
                                                   __float_as_int(r),
                                                   0x138 /*wave_shr:1*/, 0xF, 0xF, false);
      const float nb = __int_as_float(nb_i);
      const float C = A;                  // R'[i-1][j-1]
      A = nb;                             // R'[i-1][j]
      const int n = s - skew;
      const bool active = (n >= 0) && (n < M_);
      const float mn = fminf(fminf(A, B), C);
      const float e  = (exp2f(mn - A) + exp2f(mn - B)) + exp2f(mn - C);
      const float rr = (dcur[k] + mn) - log2f(e);
      r = active ? rr : BIGF;
      if (active) B = rr;
      if (pub) ringp[wr_row + (s & (RING - 1))] = r;
    }
    __syncthreads();   // also drains nx loads (issued ~16 steps ago)

#pragma unroll
    for (int k = 0; k < LAG; ++k) dcur[k] = __uint_as_float((uint)nx[k] << 16);
  }

  if (t == N_ - 1) wv[b] = exp2f(-0.1f * B);   // w = exp(-R) = 2^(-gamma*R')
}

// ---------------------------------------------------------------------------
// Kernel C: out = x * w[b], full-grid elementwise (float4).
// ---------------------------------------------------------------------------
__global__ __launch_bounds__(256) void dtw_mul_kernel(const float* __restrict__ x,
                                                      const float* __restrict__ wv,
                                                      float* __restrict__ out) {
  const int idx = blockIdx.x * 256 + threadIdx.x;   // float4 index
  const int b = idx >> 13;                          // 8192 float4 per batch
  const float w = wv[b];
  float4 v = ((const float4*)x)[idx];
  v.x *= w; v.y *= w; v.z *= w; v.w *= w;
  ((float4*)out)[idx] = v;
}

// ---------------------------------------------------------------------------
// Fallback path A' (f32 row-major D), used when ws is too small for Ds.
// ---------------------------------------------------------------------------
__global__ __launch_bounds__(256) void dtw_dist_kernel(const float* __restrict__ x,
                                                       const float* __restrict__ y,
                                                       float* __restrict__ D) {
  __shared__ float xs[128][65];
  __shared__ float ys[128][65];
  const int b  = blockIdx.z;
  const int i0 = blockIdx.y * 128;
  const int j0 = blockIdx.x * 128;
  const int tid = threadIdx.x;
  const float* xb = x + ((size_t)b * N_ + i0) * Dm_;
  const float* yb = y + ((size_t)b * M_ + j0) * Dm_;
#pragma unroll
  for (int r = 0; r < 8; ++r) {
    int v4 = tid + r * 256;
    int row = v4 >> 4, c4 = (v4 & 15) * 4;
    float4 xv = *(const float4*)(xb + (size_t)row * Dm_ + c4);
    float4 yv = *(const float4*)(yb + (size_t)row * Dm_ + c4);
    xs[row][c4 + 0] = xv.x; xs[row][c4 + 1] = xv.y;
    xs[row][c4 + 2] = xv.z; xs[row][c4 + 3] = xv.w;
    ys[row][c4 + 0] = yv.x; ys[row][c4 + 1] = yv.y;
    ys[row][c4 + 2] = yv.z; ys[row][c4 + 3] = yv.w;
  }
  __syncthreads();
  const int ty = tid >> 4, tx = tid & 15;
  float acc[8][8];
#pragma unroll
  for (int e = 0; e < 8; ++e)
#pragma unroll
    for (int f = 0; f < 8; ++f) acc[e][f] = 0.f;
#pragma unroll 4
  for (int k = 0; k < Dm_; ++k) {
    float xa[8], yv[8];
#pragma unroll
    for (int e = 0; e < 8; ++e) xa[e] = xs[ty * 8 + e][k];
#pragma unroll
    for (int f = 0; f < 8; ++f) yv[f] = ys[tx * 8 + f][k];
#pragma unroll
    for (int e = 0; e < 8; ++e)
#pragma unroll
      for (int f = 0; f < 8; ++f) {
        float t = xa[e] - yv[f];
        acc[e][f] = fmaf(t, t, acc[e][f]);
      }
  }
  float* Db = D + ((size_t)b * N_ + i0) * M_ + j0;
#pragma unroll
  for (int e = 0; e < 8; ++e) {
    const int row = ty * 8 + e;
#pragma unroll
    for (int f4 = 0; f4 < 2; ++f4) {
      float4 v4 = make_float4(acc[e][f4 * 4 + 0] * SINV, acc[e][f4 * 4 + 1] * SINV,
                              acc[e][f4 * 4 + 2] * SINV, acc[e][f4 * 4 + 3] * SINV);
      *(float4*)(Db + (size_t)row * M_ + tx * 8 + f4 * 4) = v4;
    }
  }
}

__global__ __launch_bounds__(512) void dtw_dp_kernel(const float* __restrict__ Dmat,
                                                     float* __restrict__ wv) {
  const int b    = blockIdx.x;
  const int t    = threadIdx.x;
  const int w    = t >> 6;
  const int lane = t & 63;
  const int skew = t + w * LAG;
  __shared__ float ringp[8 * RING];
  for (int q = t; q < 8 * RING; q += 512) ringp[q] = BIGF;
  __syncthreads();
  const float* Drow = Dmat + ((size_t)b * N_ + t) * M_;
  const int rd_base = ((w + 7) & 7) * RING;
  const bool pub    = (lane == 63) && (w < 7);
  const int wr_row  = w * RING;
  float A = (t == 0) ? 0.0f : BIGF;
  float B = BIGF;
  float r = BIGF;
  float dcur[LAG], dnxt[LAG];
#pragma unroll
  for (int k = 0; k < LAG; ++k) {
    int idx = k - skew; idx = idx < 0 ? 0 : idx;
    dcur[k] = Drow[idx];
  }
  const int NBLK = SPAD / LAG;
  for (int blk = 0; blk < NBLK; ++blk) {
    const int s0 = blk * LAG;
#pragma unroll
    for (int k = 0; k < LAG; ++k) {
      int idx = s0 + LAG + k - skew;
      idx = idx < 0 ? 0 : (idx > M_ - 1 ? M_ - 1 : idx);
      dnxt[k] = Drow[idx];
    }
    float rvf[LAG];
#pragma unroll
    for (int k = 0; k < LAG; ++k)
      rvf[k] = ringp[rd_base + ((s0 + k - LAG - 1) & (RING - 1))];
#pragma unroll
    for (int k = 0; k < LAG; ++k) {
      const int s = s0 + k;
      const int nb_i = __builtin_amdgcn_update_dpp(__float_as_int(rvf[k]),
                                                   __float_as_int(r),
                                                   0x138, 0xF, 0xF, false);
      const float nb = __int_as_float(nb_i);
      const float C = A;
      A = nb;
      const int n = s - skew;
      const bool active = (n >= 0) && (n < M_);
      const float mn = fminf(fminf(A, B), C);
      const float e  = (exp2f(mn - A) + exp2f(mn - B)) + exp2f(mn - C);
      const float rr = (dcur[k] + mn) - log2f(e);
      r = active ? rr : BIGF;
      if (active) B = rr;
      if (pub) ringp[wr_row + (s & (RING - 1))] = r;
    }
#pragma unroll
    for (int k = 0; k < LAG; ++k) dcur[k] = dnxt[k];
    __syncthreads();
  }
  if (t == N_ - 1) wv[b] = exp2f(-0.1f * B);
}

// ---------------------------------------------------------------------------
// Fallback path B' (no workspace): barrier-per-step fused DP.
// ---------------------------------------------------------------------------
__global__ __launch_bounds__(512) void dtw_dp_fused(const float* __restrict__ x,
                                                    const float* __restrict__ y,
                                                    float* __restrict__ out) {
  __shared__ float v[3][516];
  const int b = blockIdx.x;
  const int t = threadIdx.x;
  const int i = t + 1;
  if (t == 0) { v[0][0] = 0.f; v[1][0] = BIGF; v[2][0] = BIGF; }
  v[0][i] = BIGF;
  v[1][i] = BIGF;
  float xr[Dm_];
  const float* xrow = x + ((size_t)b * N_ + t) * Dm_;
#pragma unroll
  for (int k = 0; k < Dm_; ++k) xr[k] = xrow[k];
  __syncthreads();
  int cur = 2, m1 = 1, m2 = 0;
  const float GLN2 = 0.069314718055994531f;
  for (int p = 2; p <= N_ + M_; ++p) {
    const int j = p - i;
    const bool valid = (j >= 1) && (j <= M_);
    float d = 0.f;
    if (valid) {
      const float* yr = y + ((size_t)b * M_ + (j - 1)) * Dm_;
      float a = 0.f;
#pragma unroll
      for (int k = 0; k < Dm_; ++k) { float u = xr[k] - yr[k]; a = fmaf(u, u, a); }
      d = a;
    }
    const float a  = v[m1][i - 1];
    const float bb = v[m1][i];
    const float c  = v[m2][i - 1];
    const float mn = fminf(fminf(a, bb), c);
    const float s = exp2f((mn - a) * SINV) + exp2f((mn - bb) * SINV) +
                    exp2f((mn - c) * SINV);
    const float rr = valid ? (d + mn - GLN2 * log2f(s)) : BIGF;
    v[cur][i] = rr;
    if (t == 0) v[cur][0] = BIGF;
    __syncthreads();
    const int tmp = m2; m2 = m1; m1 = cur; cur = tmp;
  }
  const float dist = v[(N_ + M_) % 3][N_];
  const float wsc = expf(-dist);
  const float* xb = x + (size_t)b * N_ * Dm_;
  float* ob = out + (size_t)b * N_ * Dm_;
#pragma unroll
  for (int e = 0; e < (N_ * Dm_) / 512; ++e) {
    const int idx = e * 512 + t;
    ob[idx] = xb[idx] * wsc;
  }
}

// ---------------------------------------------------------------------------
extern "C" void kernel_launch(void* const* d_in, const int* in_sizes, int n_in,
                              void* d_out, int out_size, void* d_ws, size_t ws_size,
                              hipStream_t stream) {
  const float* x = (const float*)d_in[0];
  const float* y = (const float*)d_in[1];
  float* out = (float*)d_out;

  const size_t needS = (size_t)B_ * SPAD * N_ * 2;          // 74,448,896 B
  const size_t needF = (size_t)B_ * N_ * M_ * sizeof(float); // 64 MiB
  const int mul_grid = (B_ * N_ * Dm_ / 4) / 256;            // 2048

  if (ws_size >= needS + 4096) {
    __hip_bfloat16* Dsb = (__hip_bfloat16*)d_ws;
    float* wvp = (float*)((char*)d_ws + needS);
    dim3 g(M_ / 128, N_ / 128, B_);
    dtw_dist_skew<<<g, dim3(256), 0, stream>>>(x, y, Dsb);
    dtw_dp2<<<dim3(B_), dim3(512), 0, stream>>>((const ushort*)Dsb, wvp);
    dtw_mul_kernel<<<dim3(mul_grid), dim3(256), 0, stream>>>(x, wvp, out);
  } else if (ws_size >= needF + 4096) {
    float* Dbuf = (float*)d_ws;
    float* wvp  = (float*)((char*)d_ws + needF);
    dim3 g(M_ / 128, N_ / 128, B_);
    dtw_dist_kernel<<<g, dim3(256), 0, stream>>>(x, y, Dbuf);
    dtw_dp_kernel<<<dim3(B_), dim3(512), 0, stream>>>(Dbuf, wvp);
    dtw_mul_kernel<<<dim3(mul_grid), dim3(256), 0, stream>>>(x, wvp, out);
  } else {
    dtw_dp_fused<<<dim3(B_), dim3(512), 0, stream>>>(x, y, out);
  }
}